// Round 1
// 739.039 us; speedup vs baseline: 1.0213x; 1.0213x over previous
//
#include <hip/hip_runtime.h>
#include <math.h>

// Problem constants (fixed by the reference): B=32768, K=32, D=128.
#define B_ROWS 32768
#define KNBR 32
#define DDIM 128

// ws layout (floats):
//   [0,128)            v_ego = W_msg^T a[:128]
//   [128,256)          v_nbr = W_msg^T a[128:]
//   [256, 256+16384)   WmT[d*128+e] = W_msg[e*128+d]
//   [16640, 33024)     WsT[d*128+e] = W_self[e*128+d]
#define WS_VEGO 0
#define WS_VNBR 128
#define WS_WMT  256
#define WS_WST  (256 + 128*128)

__global__ __launch_bounds__(256) void prep_kernel(
    const float* __restrict__ W_msg, const float* __restrict__ W_attn,
    const float* __restrict__ W_self, float* __restrict__ ws) {
    int t = threadIdx.x;
    int gid = blockIdx.x * 256 + t;
    if (gid < 128 * 128) {
        int e = gid >> 7, d = gid & 127;
        ws[WS_WMT + d * 128 + e] = W_msg[e * 128 + d];
        ws[WS_WST + d * 128 + e] = W_self[e * 128 + d];
    }
    if (blockIdx.x == 0 && t < 128) {
        float ve = 0.f, vn = 0.f;
        for (int e = 0; e < 128; ++e) {
            float w = W_msg[e * 128 + t];
            ve += W_attn[e] * w;
            vn += W_attn[128 + e] * w;
        }
        ws[WS_VEGO + t] = ve;
        ws[WS_VNBR + t] = vn;
    }
}

// Fully fused: attention (wave-per-row, register-resident neighbour tile)
// + output GEMM epilogue. 32 rows per block; hbar never touches HBM.
//   Phase A: wave w computes hbar for rows w*8 .. w*8+7, writes to LDS.
//   Phase B: out = tanh(hbar @ WmT + h_ego @ WsT + b_self), 16 outputs/thread.
__global__ __launch_bounds__(256) void fused_kernel(
    const float* __restrict__ h_ego, const float* __restrict__ h_nei,
    const int* __restrict__ nbr_mask, const float* __restrict__ ws,
    const float* __restrict__ b_self, float* __restrict__ out) {
    __shared__ float xh[32 * DDIM];  // hbar tile, 16 KB
    __shared__ float xe[32 * DDIM];  // h_ego tile, 16 KB

    int t = threadIdx.x;
    int w = t >> 6, l = t & 63;
    long rbase = (long)blockIdx.x * 32;

    // Cooperative stage of the 32-row h_ego tile (read exactly once from HBM).
    const float4* srcE = (const float4*)(h_ego + rbase * DDIM);
#pragma unroll
    for (int i = 0; i < 4; ++i) {
        ((float4*)xe)[i * 256 + t] = srcE[i * 256 + t];
    }

    // Per-lane slices of the folded attention vectors (d = 2l, 2l+1).
    float2 vn2 = ((const float2*)(ws + WS_VNBR))[l];
    float2 ve2 = ((const float2*)(ws + WS_VEGO))[l];
    __syncthreads();

    // ---- Phase A: attention, 8 rows per wave, no further LDS use until write.
    for (int i = 0; i < 8; ++i) {
        int row = w * 8 + i;
        long b = rbase + row;

        float2 he2 = ((const float2*)xe)[row * 64 + l];

        // Stage the full neighbour row into registers: 32 independent dwordx2.
        const float2* rowp = (const float2*)(h_nei + b * (KNBR * DDIM));
        float2 hreg[KNBR];
#pragma unroll
        for (int k = 0; k < KNBR; ++k) hreg[k] = rowp[k * 64 + l];

        // Validity bitmask (wave-uniform): bit k = nbr_mask[b][k] > 0.
        int mv = nbr_mask[b * KNBR + (l & 31)];
        unsigned long long bal = __ballot((l < KNBR) && (mv > 0));
        unsigned vmask = (unsigned)bal;

        // Ego logit contribution (butterfly -> replicated in all lanes).
        float pe = he2.x * ve2.x + he2.y * ve2.y;
#pragma unroll
        for (int s = 32; s; s >>= 1) pe += __shfl_xor(pe, s, 64);

        // Neighbour logits: butterfly per k; every lane ends with all 32
        // logits, so softmax is lane-replicated (zero further communication).
        float e[KNBR];
        float m = -INFINITY;
#pragma unroll
        for (int k = 0; k < KNBR; ++k) {
            float p = hreg[k].x * vn2.x + hreg[k].y * vn2.y;
#pragma unroll
            for (int s = 32; s; s >>= 1) p += __shfl_xor(p, s, 64);
            p += pe;
            p = p > 0.f ? p : 0.2f * p;                 // leaky_relu(0.2)
            p = ((vmask >> k) & 1u) ? p : -INFINITY;
            e[k] = p;
            m = fmaxf(m, p);
        }
        float ssum = 0.f;
#pragma unroll
        for (int k = 0; k < KNBR; ++k) {
            float ev = ((vmask >> k) & 1u) ? __expf(e[k] - m) : 0.f;
            e[k] = ev;
            ssum += ev;
        }
        float inv = ssum > 0.f ? 1.f / ssum : 0.f;      // all-masked row -> 0

        // hbar slice: pure register FMA, then park in LDS for phase B.
        float2 acc = make_float2(0.f, 0.f);
#pragma unroll
        for (int k = 0; k < KNBR; ++k) {
            acc.x += e[k] * hreg[k].x;
            acc.y += e[k] * hreg[k].y;
        }
        acc.x *= inv;
        acc.y *= inv;
        ((float2*)xh)[row * 64 + l] = acc;
    }
    __syncthreads();

    // ---- Phase B: out = tanh(hbar @ WmT + h_ego @ WsT + b_self).
    const float4* WmT = (const float4*)(ws + WS_WMT);
    const float4* WsT = (const float4*)(ws + WS_WST);
    const float4* xh4 = (const float4*)xh;
    const float4* xe4 = (const float4*)xe;
    int tc = t & 31;   // col group -> e = tc*4 .. tc*4+3
    int tr = t >> 5;   // row group -> r = tr*4 .. tr*4+3

    float acc[4][4] = {{0.f}};
    for (int d4 = 0; d4 < 32; ++d4) {
        // Weights for d = 4*d4 .. 4*d4+3, shared across the 4 rows.
        float4 wm0 = WmT[(d4 * 4 + 0) * 32 + tc];
        float4 wm1 = WmT[(d4 * 4 + 1) * 32 + tc];
        float4 wm2 = WmT[(d4 * 4 + 2) * 32 + tc];
        float4 wm3 = WmT[(d4 * 4 + 3) * 32 + tc];
        float4 ws0 = WsT[(d4 * 4 + 0) * 32 + tc];
        float4 ws1 = WsT[(d4 * 4 + 1) * 32 + tc];
        float4 ws2 = WsT[(d4 * 4 + 2) * 32 + tc];
        float4 ws3 = WsT[(d4 * 4 + 3) * 32 + tc];
#pragma unroll
        for (int r = 0; r < 4; ++r) {
            float4 a = xh4[(tr * 4 + r) * 32 + d4];
            float4 g = xe4[(tr * 4 + r) * 32 + d4];
            acc[r][0] += a.x * wm0.x + a.y * wm1.x + a.z * wm2.x + a.w * wm3.x
                       + g.x * ws0.x + g.y * ws1.x + g.z * ws2.x + g.w * ws3.x;
            acc[r][1] += a.x * wm0.y + a.y * wm1.y + a.z * wm2.y + a.w * wm3.y
                       + g.x * ws0.y + g.y * ws1.y + g.z * ws2.y + g.w * ws3.y;
            acc[r][2] += a.x * wm0.z + a.y * wm1.z + a.z * wm2.z + a.w * wm3.z
                       + g.x * ws0.z + g.y * ws1.z + g.z * ws2.z + g.w * ws3.z;
            acc[r][3] += a.x * wm0.w + a.y * wm1.w + a.z * wm2.w + a.w * wm3.w
                       + g.x * ws0.w + g.y * ws1.w + g.z * ws2.w + g.w * ws3.w;
        }
    }

    float4 bv = ((const float4*)b_self)[tc];
#pragma unroll
    for (int r = 0; r < 4; ++r) {
        float4 o;
        o.x = tanhf(acc[r][0] + bv.x);
        o.y = tanhf(acc[r][1] + bv.y);
        o.z = tanhf(acc[r][2] + bv.z);
        o.w = tanhf(acc[r][3] + bv.w);
        ((float4*)(out + (rbase + tr * 4 + r) * DDIM))[tc] = o;
    }
}

extern "C" void kernel_launch(void* const* d_in, const int* in_sizes, int n_in,
                              void* d_out, int out_size, void* d_ws, size_t ws_size,
                              hipStream_t stream) {
    const float* h_ego   = (const float*)d_in[0];
    const float* h_nei   = (const float*)d_in[1];
    const int*   nbr_mask= (const int*)d_in[2];
    const float* W_msg   = (const float*)d_in[3];
    const float* W_attn  = (const float*)d_in[4];
    const float* W_self  = (const float*)d_in[5];
    const float* b_self  = (const float*)d_in[6];
    float* out = (float*)d_out;
    float* ws  = (float*)d_ws;

    prep_kernel<<<64, 256, 0, stream>>>(W_msg, W_attn, W_self, ws);
    fused_kernel<<<B_ROWS / 32, 256, 0, stream>>>(h_ego, h_nei, nbr_mask, ws,
                                                  b_self, out);
}